// Round 7
// baseline (176.063 us; speedup 1.0000x reference)
//
#include <hip/hip_runtime.h>

// SmallRNN: B=4096 chains, T=2048 steps, I=1, H=8, O=1, fp32.
// h_t = tanh(x_t*w_ih + W_hh h_{t-1} + b);  out = fc_w . h_T + fc_b
//
// Round 8 RE-RUN (previous submission hit "container failed twice" --
// infra flake, same as Round 1's, which benched clean on resubmit).
// pk-dot with ILP restored + ping-pong prefetch.
// Calibration from R4/R7 counters: full-rate VALU = 2 cyc/instr (incl.
// v_pk_fma_f32 -- 2 FLOPs/lane at full rate), trans (exp/rcp) ~20 cyc
// issue each. R7 regressed via +12 cyc stall: its 4 chained volatile pk
// statements made the dot a serial depth-4 chain. Fix: two independent
// depth-2 pk chains + pk_add combine, in ONE pure (non-volatile) asm
// block the scheduler can move things around:
//   X = pk_fma(W1,g1, pk_fma(W0,r,S))   // S=(0,xwb)
//   Y = pk_fma(W3,g3, pk_mul(W2,g2))
//   P = pk_add(X,Y)                      // 5 ops, depth 3
// (R4 scalar dot: 8 fma+mul = 9 ops depth 4.)  s_nop 1 data-chained on
// P guards the gfx9 DPP-read-after-VALU-write hazard before row_ror:8
// (R5 lesson; R7-verified).  Ping-pong x buffers remove the 16 per-group
// register copies.
//
// Layout (R4/R7-verified): 16 lanes/chain, 8 rows x 2 column-split
// replicas; lane p holds r[rho], rho=j^(4*(p>=8)); computes 4-col
// partials for rows rho (P1=hi, xwb seed) and rho^4 (P2=lo), P2
// exchanged via row_ror:8. 256 thr/block = 16 chains, grid 256 ->
// 1024 waves = 1 wave/SIMD (R6: replication refuted; single issue port).

#define B_TOTAL 4096
#define T_STEPS 2048
#define H 8

typedef float float2v __attribute__((ext_vector_type(2)));

template <int CTRL>
__device__ __forceinline__ float dppf(float v) {
    int i = __float_as_int(v);
    i = __builtin_amdgcn_mov_dpp(i, CTRL, 0xF, 0xF, true);
    return __int_as_float(i);
}

__global__ __launch_bounds__(256, 1) void rnn_fused(
    const float* __restrict__ x,      // [4096, 2048]
    const float* __restrict__ w_ih,   // [8,1]
    const float* __restrict__ w_hh,   // [8,8]
    const float* __restrict__ b_ih,   // [8]
    const float* __restrict__ b_hh,   // [8]
    const float* __restrict__ fc_w,   // [1,8]
    const float* __restrict__ fc_b,   // [1]
    float* __restrict__ out)          // [4096,1]
{
    const int tid      = threadIdx.x;
    const int p        = tid & 15;          // position within 16-lane row
    const int j        = p & 7;             // hidden index within replica
    const int rho      = j ^ ((p >> 3) << 2); // rotated row: j ^ 4 for high replica
    const int chain    = (blockIdx.x << 4) + (tid >> 4);
    const int baseLane = tid & 48;          // wave-relative base of this row

    // C = 2*log2(e): exp(2*pre) = exp2(C*pre).
    const float C = 2.885390081777927f;

    // r-state weights (r = 1/(1+exp2(C*pre)), h = 1-2r folded into W,b):
    //   W'[row][col] = -2*C*W[row][col]
    //   bP_row = C*(b_row + rowsum(W[row])),  wihC_row = C*wih_row
    // Lane p covers columns rho^{0..3}; pair Wk = (wB[k], wA[k]):
    //   wA[k] = W'[rho  ][rho^k]  (own row -> hi lane, xwb seed)
    //   wB[k] = W'[rho^4][rho^k]  (partner row -> lo lane, ror:8 exch)
    float wA[4], wB[4];
    float rowsum = 0.0f;
#pragma unroll
    for (int i = 0; i < H; ++i) rowsum += w_hh[rho * H + i];
#pragma unroll
    for (int k = 0; k < 4; ++k) {
        wA[k] = -2.0f * C * w_hh[rho * H + (rho ^ k)];
        wB[k] = -2.0f * C * w_hh[(rho ^ 4) * H + (rho ^ k)];
    }
    const float wihC = C * w_ih[rho];
    const float bP   = C * (b_ih[rho] + b_hh[rho] + rowsum);

    const float2v W0 = {wB[0], wA[0]};
    const float2v W1 = {wB[1], wA[1]};
    const float2v W2 = {wB[2], wA[2]};
    const float2v W3 = {wB[3], wA[3]};

    const float* xp = x + (size_t)chain * T_STEPS;

    // Pair-resident state; only .x of rp/g* is read (op_sel_hi broadcasts
    // word0 into the hi half). .y kept initialized.
    float2v rp  = {0.5f, 0.0f};   // r: h = 1-2r = 0
    float2v S   = {0.0f, 0.0f};   // seed pair (0, xwb); .x stays 0 forever
    float2v g1p = {0.0f, 0.0f};
    float2v g2p = {0.0f, 0.0f};
    float2v g3p = {0.0f, 0.0f};

    // One RNN step, ~12 instructions:
    //   xwb fma (off-path) | 3 quad_perm gathers (builtin DPP) |
    //   5-op pk block: two depth-2 chains + pk_add, s_nop hazard guard |
    //   ror:8 exchange (builtin) | add | exp2 | add | rcp.
#define STEP(xval)                                                           \
    {                                                                        \
        S.y = fmaf((xval), wihC, bP);        /* off-path seed */             \
        g1p.x = dppf<0xB1>(rp.x);            /* r[rho^1] */                  \
        g2p.x = dppf<0x4E>(rp.x);            /* r[rho^2] */                  \
        g3p.x = dppf<0x1B>(rp.x);            /* r[rho^3] */                  \
        float2v P, X, Y;                                                     \
        asm("v_pk_fma_f32 %1, %3, %7, %4 op_sel_hi:[1,0,1]\n\t"              \
            "v_pk_mul_f32 %2, %5, %9 op_sel_hi:[1,0]\n\t"                    \
            "v_pk_fma_f32 %1, %6, %8, %1 op_sel_hi:[1,0,1]\n\t"              \
            "v_pk_fma_f32 %2, %10, %11, %2 op_sel_hi:[1,0,1]\n\t"            \
            "v_pk_add_f32 %0, %1, %2\n\t"                                    \
            "s_nop 1"                                                        \
            : "=v"(P), "=&v"(X), "=&v"(Y)                                    \
            : "v"(W0), "v"(S), "v"(W2), "v"(W1),                             \
              "v"(rp), "v"(g1p), "v"(g2p), "v"(W3), "v"(g3p));               \
        float p2x = dppf<0x128>(P.x);        /* partner's P2 (XOR8) */       \
        float s = P.y + p2x;                                                 \
        float e = __builtin_amdgcn_exp2f(s);                                 \
        rp.x = __builtin_amdgcn_rcpf(1.0f + e);                              \
    }

    // Ping-pong prefetch: 32 steps per iteration, two 16-value buffers.
    float4 a0 = *(const float4*)(xp + 0);
    float4 a1 = *(const float4*)(xp + 4);
    float4 a2 = *(const float4*)(xp + 8);
    float4 a3 = *(const float4*)(xp + 12);
    float4 b0, b1, b2, b3;

    for (int t = 0; t < T_STEPS; t += 32) {
        // buf B <- x[t+16 .. t+32)   (t+16 <= 2032 < 2048 always)
        b0 = *(const float4*)(xp + t + 16);
        b1 = *(const float4*)(xp + t + 20);
        b2 = *(const float4*)(xp + t + 24);
        b3 = *(const float4*)(xp + t + 28);
        STEP(a0.x) STEP(a0.y) STEP(a0.z) STEP(a0.w)
        STEP(a1.x) STEP(a1.y) STEP(a1.z) STEP(a1.w)
        STEP(a2.x) STEP(a2.y) STEP(a2.z) STEP(a2.w)
        STEP(a3.x) STEP(a3.y) STEP(a3.z) STEP(a3.w)
        // buf A <- x[t+32 .. t+48)   (skip on last iteration)
        if (t + 32 < T_STEPS) {
            a0 = *(const float4*)(xp + t + 32);
            a1 = *(const float4*)(xp + t + 36);
            a2 = *(const float4*)(xp + t + 40);
            a3 = *(const float4*)(xp + t + 44);
        }
        STEP(b0.x) STEP(b0.y) STEP(b0.z) STEP(b0.w)
        STEP(b1.x) STEP(b1.y) STEP(b1.z) STEP(b1.w)
        STEP(b2.x) STEP(b2.y) STEP(b2.z) STEP(b2.w)
        STEP(b3.x) STEP(b3.y) STEP(b3.z) STEP(b3.w)
    }
#undef STEP

    // Final h from r-state; lanes p=0..7 hold rows rho=0..7 (low replica).
    float h = fmaf(-2.0f, rp.x, 1.0f);
    float g[H];
#pragma unroll
    for (int k = 0; k < H; ++k) g[k] = __shfl(h, baseLane + k);
    if (p == 0) {
        float o = fc_b[0];
#pragma unroll
        for (int k = 0; k < H; ++k) o = fmaf(fc_w[k], g[k], o);
        out[chain] = o;
    }
}

extern "C" void kernel_launch(void* const* d_in, const int* in_sizes, int n_in,
                              void* d_out, int out_size, void* d_ws, size_t ws_size,
                              hipStream_t stream) {
    const float* x    = (const float*)d_in[0];
    const float* w_ih = (const float*)d_in[1];
    const float* w_hh = (const float*)d_in[2];
    const float* b_ih = (const float*)d_in[3];
    const float* b_hh = (const float*)d_in[4];
    const float* fc_w = (const float*)d_in[5];
    const float* fc_b = (const float*)d_in[6];
    float* out = (float*)d_out;

    dim3 grid(B_TOTAL / 16);   // 256 blocks -> 1 per CU
    dim3 block(256);           // 4 waves -> 1 per SIMD
    hipLaunchKernelGGL(rnn_fused, grid, block, 0, stream,
                       x, w_ih, w_hh, b_ih, b_hh, fc_w, fc_b, out);
}

// Round 8
// 162.368 us; speedup vs baseline: 1.0843x; 1.0843x over previous
//
#include <hip/hip_runtime.h>

// SmallRNN: B=4096 chains, T=2048 steps, I=1, H=8, O=1, fp32.
// h_t = tanh(x_t*w_ih + W_hh h_{t-1} + b);  out = fc_w . h_T + fc_b
//
// Round 9: R4-verified skeleton + shallow dot (depth 4 -> 2) + add3.
// Closed paths (measured): R6 wave replication (single issue port,
// 92->154); R5 asm DPP-fusion (hazard corruption); R7/R8 pk-asm (issue
// win < scheduler loss from asm opacity; R8's monolithic block +40 cyc
// stall). Model: 108 cyc/step with issue 73 (31 VALU + 2 trans x ~21)
// BALANCED against dependency chain ~75-100. This round cuts the chain
// only, in pure C/builtins so the compiler keeps software-pipelining
// across the 16-step unroll:
//   p1 = ((wA0*r+xwb) + wA1*g1) + (wA2*g2 + wA3*g3)   depth 2 halves
//   p2 likewise; s = u + v + p2x  -> LLVM folds to v_add3_f32.
// Post-gather chain ~26 -> ~20 cyc. Arithmetic re-associated only
// (outputs compared in bf16 -> ulp changes invisible).
//
// Layout (R4-verified): 16 lanes/chain, 8 rows x 2 column-split
// replicas; lane p holds r[rho], rho=j^(4*(p>=8)); computes 4-col
// partials for rows rho (P1, xwb seed) and rho^4 (P2), P2 exchanged
// via row_ror:8 (+-8 mod 16 == XOR8 either direction). 256 thr/block
// = 16 chains, grid 256 -> 1024 waves = 1 wave/SIMD.

#define B_TOTAL 4096
#define T_STEPS 2048
#define H 8

template <int CTRL>
__device__ __forceinline__ float dppf(float v) {
    int i = __float_as_int(v);
    i = __builtin_amdgcn_mov_dpp(i, CTRL, 0xF, 0xF, true);
    return __int_as_float(i);
}

__global__ __launch_bounds__(256, 1) void rnn_fused(
    const float* __restrict__ x,      // [4096, 2048]
    const float* __restrict__ w_ih,   // [8,1]
    const float* __restrict__ w_hh,   // [8,8]
    const float* __restrict__ b_ih,   // [8]
    const float* __restrict__ b_hh,   // [8]
    const float* __restrict__ fc_w,   // [1,8]
    const float* __restrict__ fc_b,   // [1]
    float* __restrict__ out)          // [4096,1]
{
    const int tid      = threadIdx.x;
    const int p        = tid & 15;          // position within 16-lane row
    const int j        = p & 7;             // hidden index within replica
    const int rho      = j ^ ((p >> 3) << 2); // rotated row: j ^ 4 for high replica
    const int chain    = (blockIdx.x << 4) + (tid >> 4);
    const int baseLane = tid & 48;          // wave-relative base of this row

    // C = 2*log2(e): exp(2*pre) = exp2(C*pre).
    const float C = 2.885390081777927f;

    // r-state weights (r = 1/(1+exp2(C*pre)), h = 1-2r folded into W,b):
    //   W'[row][col] = -2*C*W[row][col]
    //   bP_row = C*(b_row + rowsum(W[row])),  wihC_row = C*wih_row
    // Lane p covers columns rho^{0..3}:
    //   wA[k] = W'[rho  ][rho^k]  (own row,     xwb seed)
    //   wB[k] = W'[rho^4][rho^k]  (partner row, ror:8 exchange)
    float wA[4], wB[4];
    float rowsum = 0.0f;
#pragma unroll
    for (int i = 0; i < H; ++i) rowsum += w_hh[rho * H + i];
#pragma unroll
    for (int k = 0; k < 4; ++k) {
        wA[k] = -2.0f * C * w_hh[rho * H + (rho ^ k)];
        wB[k] = -2.0f * C * w_hh[(rho ^ 4) * H + (rho ^ k)];
    }
    const float wihC = C * w_ih[rho];
    const float bP   = C * (b_ih[rho] + b_hh[rho] + rowsum);

    const float* xp = x + (size_t)chain * T_STEPS;

    float r = 0.5f;   // h = 1 - 2r = 0 for every row

    // One RNN step. Shallow dot: two independent depth-2 halves per
    // partial; combine via add / add3 (compiler-formed). All builtins.
#define STEP(xval)                                          \
    {                                                       \
        float xwb = fmaf((xval), wihC, bP);  /* off-path */ \
        float g1 = dppf<0xB1>(r);    /* r[rho^1] */         \
        float g2 = dppf<0x4E>(r);    /* r[rho^2] */         \
        float g3 = dppf<0x1B>(r);    /* r[rho^3] */         \
        float u2 = wB[0] * r;                               \
        float v2 = wB[2] * g2;                              \
        u2 = fmaf(wB[1], g1, u2);                           \
        v2 = fmaf(wB[3], g3, v2);                           \
        float u1 = fmaf(wA[0], r, xwb);                     \
        float v1 = wA[2] * g2;                              \
        u1 = fmaf(wA[1], g1, u1);                           \
        v1 = fmaf(wA[3], g3, v1);                           \
        float p2 = u2 + v2;                                 \
        float p2x = dppf<0x128>(p2); /* partner P2 (XOR8) */\
        float s = (u1 + v1) + p2x;   /* -> v_add3_f32 */    \
        float e = __builtin_amdgcn_exp2f(s);                \
        r = __builtin_amdgcn_rcpf(1.0f + e);                \
    }

    // 16-step unroll; prefetch the next 16 x-values a full group ahead
    // (R4's verified loop shape).
    float4 c0 = *(const float4*)(xp + 0);
    float4 c1v = *(const float4*)(xp + 4);
    float4 c2v = *(const float4*)(xp + 8);
    float4 c3v = *(const float4*)(xp + 12);

    for (int t = 0; t < T_STEPS; t += 16) {
        float4 n0 = c0, n1 = c1v, n2 = c2v, n3 = c3v;
        if (t + 16 < T_STEPS) {
            n0 = *(const float4*)(xp + t + 16);
            n1 = *(const float4*)(xp + t + 20);
            n2 = *(const float4*)(xp + t + 24);
            n3 = *(const float4*)(xp + t + 28);
        }
        STEP(c0.x) STEP(c0.y) STEP(c0.z) STEP(c0.w)
        STEP(c1v.x) STEP(c1v.y) STEP(c1v.z) STEP(c1v.w)
        STEP(c2v.x) STEP(c2v.y) STEP(c2v.z) STEP(c2v.w)
        STEP(c3v.x) STEP(c3v.y) STEP(c3v.z) STEP(c3v.w)
        c0 = n0; c1v = n1; c2v = n2; c3v = n3;
    }
#undef STEP

    // Final h from r-state; lanes p=0..7 hold rows rho=0..7 (low replica).
    float h = fmaf(-2.0f, r, 1.0f);
    float g[H];
#pragma unroll
    for (int k = 0; k < H; ++k) g[k] = __shfl(h, baseLane + k);
    if (p == 0) {
        float o = fc_b[0];
#pragma unroll
        for (int k = 0; k < H; ++k) o = fmaf(fc_w[k], g[k], o);
        out[chain] = o;
    }
}

extern "C" void kernel_launch(void* const* d_in, const int* in_sizes, int n_in,
                              void* d_out, int out_size, void* d_ws, size_t ws_size,
                              hipStream_t stream) {
    const float* x    = (const float*)d_in[0];
    const float* w_ih = (const float*)d_in[1];
    const float* w_hh = (const float*)d_in[2];
    const float* b_ih = (const float*)d_in[3];
    const float* b_hh = (const float*)d_in[4];
    const float* fc_w = (const float*)d_in[5];
    const float* fc_b = (const float*)d_in[6];
    float* out = (float*)d_out;

    dim3 grid(B_TOTAL / 16);   // 256 blocks -> 1 per CU
    dim3 block(256);           // 4 waves -> 1 per SIMD
    hipLaunchKernelGGL(rnn_fused, grid, block, 0, stream,
                       x, w_ih, w_hh, b_ih, b_hh, fc_w, fc_b, out);
}